// Round 2
// baseline (190.394 us; speedup 1.0000x reference)
//
#include <hip/hip_runtime.h>
#include <hip/hip_bf16.h>
#include <math.h>

#define B_   128
#define Qn   30
#define Dn   200
#define En   300

typedef __attribute__((ext_vector_type(8))) short short8;
typedef __attribute__((ext_vector_type(4))) float floatx4;
typedef unsigned int u32;
typedef unsigned short u16;

static __device__ __forceinline__ u16 f2b(float x) {   // fp32 -> bf16 RNE
    union { float f; u32 u; } v; v.f = x;
    u32 r = v.u + 0x7FFFu + ((v.u >> 16) & 1u);
    return (u16)(r >> 16);
}
static __device__ __forceinline__ float bits2f(u32 u) {
    union { u32 u2; float f; } v; v.u2 = u; return v.f;
}

// ---------------------------------------------------------------------------
// prep: weight permute ONLY. ks-major layout, one K-slice = contiguous 48 KB:
//   Wt3[ks 10][ g1 j0 (8 chunks) | g2 j0,j1 (16) | g3 j0..j2 (24) ] x 1KB
// chunk content: [nt 8][q4 4][c16 16][k8 8] bf16, ch = nt*16+c16,
// e = ks*32+q4*8+k8.  (unchanged from R1)
// ---------------------------------------------------------------------------
__global__ void prep_kernel(
    const float* __restrict__ w1, const float* __restrict__ w2, const float* __restrict__ w3,
    u16* __restrict__ Wt3)
{
    int p = (blockIdx.x*128 + blockIdx.y)*256 + threadIdx.x;
    if (p >= 245760) return;
    int ks = p / 24576;
    int r  = p - ks*24576;
    int g, rr;
    if (r < 4096)        { g = 0; rr = r;         }
    else if (r < 12288)  { g = 1; rr = r - 4096;  }
    else                 { g = 2; rr = r - 12288; }
    int j  = rr >> 12;
    int r2 = rr & 4095;
    int nt  = r2 >> 9;
    int q4  = (r2 >> 7) & 3;
    int c16 = (r2 >> 3) & 15;
    int k8  = r2 & 7;
    int ch = nt*16 + c16;
    int e  = ks*32 + q4*8 + k8;
    float v = 0.f;
    if (e < En) {
        if (g == 0)      v = w1[ch*En + e];
        else if (g == 1) v = w2[(ch*En + e)*2 + j];
        else             v = w3[(ch*En + e)*3 + j];
    }
    Wt3[p] = f2b(v);
}

// ---------------------------------------------------------------------------
// Fused conv, R2: NO weight LDS staging, NO K-loop barriers.
// Weights (480 KB total, shared by all 512 blocks) are L2-resident: each
// wave loads its B fragments directly to registers as coalesced 1 KB
// global_load_dwordx4 (12 per K-slice). LDS = A tile only (43.6 KB static)
// -> 2 blocks/CU (16 waves/CU) vs R1's 1 block/CU + 10 vmcnt(0) drains.
// A gathered straight from emb into LDS in the prologue (as R1).
// MFMA accumulation order per output identical to R1 => bit-identical.
// Epilogue: per-gram Gs overlay on As (17.4 KB), norms + coalesced stores.
// ---------------------------------------------------------------------------
__global__ __launch_bounds__(512, 4) void conv_kernel(
    const int* __restrict__ qtok, const int* __restrict__ dtok,
    const float* __restrict__ emb,
    const u16* __restrict__ Wt3,
    const float* __restrict__ b1, const float* __restrict__ b2, const float* __restrict__ b3,
    u16* __restrict__ qg, u16* __restrict__ dg,
    float* __restrict__ invnq, float* __restrict__ invnd)
{
    __shared__ __align__(16) char smem[43560];   // As [66][656] + toks[66]
    char* As  = smem;
    int*  toks = (int*)(smem + 43296);

    const int tile = blockIdx.x;
    const int tid = threadIdx.x;
    const int wv = tid >> 6, lane = tid & 63;
    const int l15 = lane & 15, qd4 = lane >> 4;
    const int mh = wv >> 2, nh = wv & 3;
    const int gR0 = tile*64;

    // tokens for the 66 staged rows (taps need +2)
    if (tid < 66) {
        int gr = gR0 + tid;
        int t = -1;
        if (gr < 32768) {
            int b = gr >> 8, pos = gr & 255;
            if (pos < Dn) t = dtok[b*Dn + pos];
            else if (pos >= 208 && pos < 238) t = qtok[b*Qn + (pos - 208)];
        }
        toks[tid] = t;
    }
    __syncthreads();

    // gather A: 66 rows x 80 col4 (cols >= 75 and masked rows -> zero;
    // K cols 300..319 MUST be zero since W is zero there but 0*NaN != 0)
    #pragma unroll
    for (int i = 0; i < 11; ++i) {
        int idx = tid + i*512;
        if (idx < 5280) {
            int r = idx / 80, c4 = idx - r*80;
            int t = toks[r];
            u16 o0=0,o1=0,o2=0,o3=0;
            if (t >= 0 && c4 < 75) {
                float4 v = *(const float4*)(emb + t*En + c4*4);
                o0=f2b(v.x); o1=f2b(v.y); o2=f2b(v.z); o3=f2b(v.w);
            }
            u16* pdst = (u16*)(As + r*656 + c4*8);
            pdst[0]=o0; pdst[1]=o1; pdst[2]=o2; pdst[3]=o3;
        }
    }

    float bias[3][2];
    #pragma unroll
    for (int nt = 0; nt < 2; ++nt) {
        int ch = nh*32 + nt*16 + l15;
        bias[0][nt] = b1[ch];
        bias[1][nt] = b2[ch];
        bias[2][nt] = b3[ch];
    }

    floatx4 acc[3][2][2];
    #pragma unroll
    for (int g = 0; g < 3; ++g)
        #pragma unroll
        for (int mt = 0; mt < 2; ++mt)
            #pragma unroll
            for (int nt = 0; nt < 2; ++nt)
                acc[g][mt][nt] = (floatx4){0.f,0.f,0.f,0.f};

    __syncthreads();                        // A ready; only barrier before epilogue

    #pragma unroll 1
    for (int ks = 0; ks < 10; ++ks) {
        short8 af[2][3];                    // tap-shifted A rows shared by grams
        #pragma unroll
        for (int mt = 0; mt < 2; ++mt)
            #pragma unroll
            for (int j = 0; j < 3; ++j)
                af[mt][j] = *(const short8*)(As + (mh*32 + mt*16 + l15 + j)*656 + ks*64 + qd4*16);
        const u16* Wks = Wt3 + ks*24576;    // 48 KB K-slice, L2-hot
        #pragma unroll
        for (int g = 0; g < 3; ++g) {
            const int cbW = (g == 0) ? 0 : (g == 1) ? 4096 : 12288;  // u16 units
            #pragma unroll
            for (int j = 0; j <= g; ++j) {
                const u16* bb = Wks + cbW + (j*8 + nh*2)*512 + lane*8;
                short8 w0  = *(const short8*)(bb);
                short8 w1v = *(const short8*)(bb + 512);
                #pragma unroll
                for (int mt = 0; mt < 2; ++mt) {
                    acc[g][mt][0] = __builtin_amdgcn_mfma_f32_16x16x32_bf16(
                        af[mt][j], w0,  acc[g][mt][0], 0, 0, 0);
                    acc[g][mt][1] = __builtin_amdgcn_mfma_f32_16x16x32_bf16(
                        af[mt][j], w1v, acc[g][mt][1], 0, 0, 0);
                }
            }
        }
    }

    // epilogue: per-gram Gs overlay on As (dead after K loop)
    u16* Gs = (u16*)smem;                   // [64][136]
    #pragma unroll 1
    for (int g = 0; g < 3; ++g) {
        __syncthreads();                    // Gs region free (A reads / prev g done)
        #pragma unroll
        for (int mt = 0; mt < 2; ++mt)
            #pragma unroll
            for (int nt = 0; nt < 2; ++nt) {
                int ch = nh*32 + nt*16 + l15;
                #pragma unroll
                for (int i = 0; i < 4; ++i) {
                    int row = mh*32 + mt*16 + qd4*4 + i;
                    Gs[row*136 + ch] = f2b(fmaxf(acc[g][mt][nt][i] + bias[g][nt], 0.f));
                }
            }
        __syncthreads();

        if (tid < 64) {
            const char* rp = (const char*)Gs + tid*272;
            float ssum = 0.f;
            #pragma unroll
            for (int t16 = 0; t16 < 16; ++t16) {
                uint4 u = *(const uint4*)(rp + t16*16);
                float x;
                x = bits2f(u.x << 16); ssum += x*x;  x = bits2f(u.x & 0xffff0000u); ssum += x*x;
                x = bits2f(u.y << 16); ssum += x*x;  x = bits2f(u.y & 0xffff0000u); ssum += x*x;
                x = bits2f(u.z << 16); ssum += x*x;  x = bits2f(u.z & 0xffff0000u); ssum += x*x;
                x = bits2f(u.w << 16); ssum += x*x;  x = bits2f(u.w & 0xffff0000u); ssum += x*x;
            }
            float inv = 1.f / (sqrtf(ssum) + 1e-13f);
            int gr = gR0 + tid;
            int b = gr >> 8, pos = gr & 255;
            if (pos < 208)      invnd[(g*B_ + b)*208 + pos] = inv;
            else if (pos < 238) invnq[(g*B_ + b)*32 + (pos - 208)] = inv;
        }
        #pragma unroll
        for (int i = 0; i < 2; ++i) {
            int idx = tid + i*512;          // 64 rows x 16 uint4
            int r = idx >> 4, c16 = idx & 15;
            uint4 v = *(const uint4*)((const char*)Gs + r*272 + c16*16);
            int gr = gR0 + r;
            int b = gr >> 8, pos = gr & 255;
            if (pos < 208)      *(uint4*)(dg + ((g*B_ + b)*208 + pos)*128 + c16*8) = v;
            else if (pos < 238) *(uint4*)(qg + ((g*B_ + b)*32 + (pos - 208))*128 + c16*8) = v;
        }
    }
}

// ---------------------------------------------------------------------------
// Pool: block per (dj, b); grid (3, 128) -> 384 blocks.  (unchanged)
// ---------------------------------------------------------------------------
__global__ __launch_bounds__(256, 2) void pool_kernel(
    const u16* __restrict__ qg, const u16* __restrict__ dg,
    const float* __restrict__ invnq, const float* __restrict__ invnd,
    const int* __restrict__ qtok, const int* __restrict__ dtok,
    float* __restrict__ feats)
{
    __shared__ __align__(16) u16 dsb[208*136];     // 56576 B
    __shared__ float pk[96*12];                    // 4608 B
    __shared__ float invqA[96];
    __shared__ float qmA[96];
    __shared__ __align__(16) float invd[208];

    const int tid = threadIdx.x;
    const int b = blockIdx.y, dj = blockIdx.x;
    const int wv = tid >> 6, lane = tid & 63;
    const int l15 = lane & 15, qd4 = lane >> 4;

    for (int idx = tid; idx < 208*16; idx += 256) {
        int r = idx >> 4, ch = idx & 15;
        uint4 v = make_uint4(0u,0u,0u,0u);
        if (r < Dn) v = *(const uint4*)(dg + ((dj*B_ + b)*208 + r)*128 + ch*8);
        *(uint4*)((char*)dsb + r*272 + ch*16) = v;
    }
    if (tid < 208) {
        float v = invnd[(dj*B_ + b)*208 + tid];
        bool ok = (tid < Dn) && (dtok[b*Dn + tid] > 0);
        invd[tid] = ok ? v : (-fabsf(v) - 1.0f);   // strictly negative if masked
    }
    if (tid < 96) {
        int qi = tid >> 5, qr = tid & 31;
        float v = invnq[(qi*B_ + b)*32 + qr];
        bool ok = (qr < Qn) && (qtok[b*Qn + qr] > 0);
        invqA[tid] = ok ? v : 0.f;
        qmA[tid] = ok ? 1.f : 0.f;
    }
    for (int i = tid; i < 96*12; i += 256) pk[i] = 0.f;
    __syncthreads();

    // chain constants C_k = exp(10*(mu_k + mu_{k+1})), mu: 0.9,0.7,...,-0.9
    const float CkR[9] = {8886110.5f, 162754.79f, 2980.958f, 54.598150f, 1.0f,
                          0.018315639f, 3.3546263e-4f, 6.1442124e-6f, 1.1253517e-7f};

    for (int qi = 0; qi < 3; ++qi) {
        short8 qf[2][4];
        float vq[2];
        #pragma unroll
        for (int qt = 0; qt < 2; ++qt) {
            vq[qt] = invqA[qi*32 + qt*16 + l15];
            #pragma unroll
            for (int ks = 0; ks < 4; ++ks)
                qf[qt][ks] = *(const short8*)(qg + ((qi*B_ + b)*32 + qt*16 + l15)*128 + ks*32 + qd4*8);
        }
        float pkl[2][11];
        #pragma unroll
        for (int qt = 0; qt < 2; ++qt)
            #pragma unroll
            for (int k = 0; k < 11; ++k) pkl[qt][k] = 0.f;

        for (int t = wv; t < 13; t += 4) {
            short8 af[4];
            #pragma unroll
            for (int ks = 0; ks < 4; ++ks)
                af[ks] = *(const short8*)((const char*)dsb + (t*16 + l15)*272 + ks*64 + qd4*16);
            floatx4 acc[2];
            acc[0] = (floatx4){0.f,0.f,0.f,0.f};
            acc[1] = (floatx4){0.f,0.f,0.f,0.f};
            #pragma unroll
            for (int ks = 0; ks < 4; ++ks)
                #pragma unroll
                for (int qt = 0; qt < 2; ++qt)
                    acc[qt] = __builtin_amdgcn_mfma_f32_16x16x32_bf16(af[ks], qf[qt][ks], acc[qt], 0, 0, 0);
            floatx4 iv4 = *(const floatx4*)(invd + t*16 + qd4*4);
            #pragma unroll
            for (int qt = 0; qt < 2; ++qt)
                #pragma unroll
                for (int i = 0; i < 4; ++i) {
                    float cs = acc[qt][i] * vq[qt] * iv4[i];
                    cs = (cs > 0.f) ? cs : 2.0f;   // masked/zero -> all kernels ~0
                    float t0 = cs - 1.0f;
                    float u  = cs - 0.9f;
                    float s0 = __expf(-500000.f * t0 * t0);
                    float e  = __expf(-50.f * u * u);
                    float rr = __expf(-20.f * cs);
                    pkl[qt][0] += s0;
                    pkl[qt][1] += e;
                    #pragma unroll
                    for (int kk = 0; kk < 9; ++kk) {
                        e = e * rr * CkR[kk];
                        pkl[qt][2 + kk] += e;
                    }
                }
        }
        #pragma unroll
        for (int qt = 0; qt < 2; ++qt)
            #pragma unroll
            for (int k = 0; k < 11; ++k) {
                float v = pkl[qt][k];
                v += __shfl_xor(v, 16);
                v += __shfl_xor(v, 32);
                if (qd4 == 0) atomicAdd(&pk[(qi*32 + qt*16 + l15)*12 + k], v);
            }
    }
    __syncthreads();

    if (tid < 33) {
        int qi = tid / 11, k = tid - qi*11;
        float s = 0.f;
        for (int q = 0; q < Qn; ++q)
            s += qmA[qi*32 + q] * 0.01f * __logf(fmaxf(pk[(qi*32 + q)*12 + k], 1e-10f));
        feats[(b*9 + qi*3 + dj)*11 + k] = s;
    }
}

// ---------------------------------------------------------------------------
__global__ void final_kernel(const float* __restrict__ feats,
                             const float* __restrict__ dw,
                             float* __restrict__ out) {
    int b = threadIdx.x;
    if (b < B_) {
        float s = 0.f;
        for (int f = 0; f < 99; ++f) s += feats[b*99 + f] * dw[f];
        out[b] = s;
    }
}

extern "C" void kernel_launch(void* const* d_in, const int* in_sizes, int n_in,
                              void* d_out, int out_size, void* d_ws, size_t ws_size,
                              hipStream_t stream) {
    const int*   qtok = (const int*)d_in[0];
    const int*   dtok = (const int*)d_in[1];
    const float* emb  = (const float*)d_in[2];
    const float* w1   = (const float*)d_in[3];
    const float* w2   = (const float*)d_in[4];
    const float* w3   = (const float*)d_in[5];
    const float* b1   = (const float*)d_in[6];
    const float* b2   = (const float*)d_in[7];
    const float* b3   = (const float*)d_in[8];
    const float* dw   = (const float*)d_in[9];
    float* out = (float*)d_out;

    char* w = (char*)d_ws;
    u16*   Wt3   = (u16*)w;                      // 491,520 B
    u16*   qg    = (u16*)(w + 491520);           // 3*128*32*128*2  = 3,145,728
    u16*   dgm   = (u16*)(w + 3637248);          // 3*128*208*128*2 = 20,447,232
    float* invq_ = (float*)(w + 24084480);       // 49,152
    float* invd_ = (float*)(w + 24133632);       // 319,488
    float* feats = (float*)(w + 24453120);       // 50,688 -> total 24,503,808

    prep_kernel<<<dim3(8, B_), 256, 0, stream>>>(w1, w2, w3, Wt3);

    conv_kernel<<<dim3(512), 512, 0, stream>>>(
        qtok, dtok, emb, Wt3, b1, b2, b3, qg, dgm, invq_, invd_);

    pool_kernel<<<dim3(3, B_), 256, 0, stream>>>(qg, dgm, invq_, invd_, qtok, dtok, feats);

    final_kernel<<<1, 128, 0, stream>>>(feats, dw, out);
}

// Round 3
// 166.335 us; speedup vs baseline: 1.1446x; 1.1446x over previous
//
#include <hip/hip_runtime.h>
#include <hip/hip_bf16.h>
#include <math.h>

#define B_   128
#define Qn   30
#define Dn   200
#define En   300

typedef __attribute__((ext_vector_type(8))) short short8;
typedef __attribute__((ext_vector_type(4))) float floatx4;
typedef unsigned int u32;
typedef unsigned short u16;

static __device__ __forceinline__ u16 f2b(float x) {   // fp32 -> bf16 RNE
    union { float f; u32 u; } v; v.f = x;
    u32 r = v.u + 0x7FFFu + ((v.u >> 16) & 1u);
    return (u16)(r >> 16);
}
static __device__ __forceinline__ float bits2f(u32 u) {
    union { u32 u2; float f; } v; v.u2 = u; return v.f;
}

// ---------------------------------------------------------------------------
// prep: weight permute ONLY. ks-major layout, one K-slice = contiguous 48 KB:
//   Wt3[ks 10][ g1 j0 (8 chunks) | g2 j0,j1 (16) | g3 j0..j2 (24) ] x 1KB
// chunk content: [nt 8][q4 4][c16 16][k8 8] bf16, ch = nt*16+c16,
// e = ks*32+q4*8+k8.
// ---------------------------------------------------------------------------
__global__ void prep_kernel(
    const float* __restrict__ w1, const float* __restrict__ w2, const float* __restrict__ w3,
    u16* __restrict__ Wt3)
{
    int p = (blockIdx.x*128 + blockIdx.y)*256 + threadIdx.x;
    if (p >= 245760) return;
    int ks = p / 24576;
    int r  = p - ks*24576;
    int g, rr;
    if (r < 4096)        { g = 0; rr = r;         }
    else if (r < 12288)  { g = 1; rr = r - 4096;  }
    else                 { g = 2; rr = r - 12288; }
    int j  = rr >> 12;
    int r2 = rr & 4095;
    int nt  = r2 >> 9;
    int q4  = (r2 >> 7) & 3;
    int c16 = (r2 >> 3) & 15;
    int k8  = r2 & 7;
    int ch = nt*16 + c16;
    int e  = ks*32 + q4*8 + k8;
    float v = 0.f;
    if (e < En) {
        if (g == 0)      v = w1[ch*En + e];
        else if (g == 1) v = w2[(ch*En + e)*2 + j];
        else             v = w3[(ch*En + e)*3 + j];
    }
    Wt3[p] = f2b(v);
}

// ---------------------------------------------------------------------------
// Fused conv, R3: R2 structure (no weight LDS staging, no K-loop barriers,
// B fragments read direct from L2-resident Wt3) with the R2 scratch-spill
// bug fixed: the epilogue gram loop is fully unrolled so acc[]/bias[] are
// ALWAYS compile-time indexed (rule #20 — runtime index sent the 48-reg
// accumulator array to scratch: +104 MB WRITE_SIZE, +26 MB FETCH_SIZE).
// MFMA accumulation order per output identical => bit-identical results.
// ---------------------------------------------------------------------------
__global__ __launch_bounds__(512, 4) void conv_kernel(
    const int* __restrict__ qtok, const int* __restrict__ dtok,
    const float* __restrict__ emb,
    const u16* __restrict__ Wt3,
    const float* __restrict__ b1, const float* __restrict__ b2, const float* __restrict__ b3,
    u16* __restrict__ qg, u16* __restrict__ dg,
    float* __restrict__ invnq, float* __restrict__ invnd)
{
    __shared__ __align__(16) char smem[43560];   // As [66][656] + toks[66]
    char* As  = smem;
    int*  toks = (int*)(smem + 43296);

    const int tile = blockIdx.x;
    const int tid = threadIdx.x;
    const int wv = tid >> 6, lane = tid & 63;
    const int l15 = lane & 15, qd4 = lane >> 4;
    const int mh = wv >> 2, nh = wv & 3;
    const int gR0 = tile*64;

    // tokens for the 66 staged rows (taps need +2)
    if (tid < 66) {
        int gr = gR0 + tid;
        int t = -1;
        if (gr < 32768) {
            int b = gr >> 8, pos = gr & 255;
            if (pos < Dn) t = dtok[b*Dn + pos];
            else if (pos >= 208 && pos < 238) t = qtok[b*Qn + (pos - 208)];
        }
        toks[tid] = t;
    }
    __syncthreads();

    // gather A: 66 rows x 80 col4 (cols >= 75 and masked rows -> zero;
    // K cols 300..319 MUST be zero since W is zero there but 0*NaN != 0)
    #pragma unroll
    for (int i = 0; i < 11; ++i) {
        int idx = tid + i*512;
        if (idx < 5280) {
            int r = idx / 80, c4 = idx - r*80;
            int t = toks[r];
            u16 o0=0,o1=0,o2=0,o3=0;
            if (t >= 0 && c4 < 75) {
                float4 v = *(const float4*)(emb + t*En + c4*4);
                o0=f2b(v.x); o1=f2b(v.y); o2=f2b(v.z); o3=f2b(v.w);
            }
            u16* pdst = (u16*)(As + r*656 + c4*8);
            pdst[0]=o0; pdst[1]=o1; pdst[2]=o2; pdst[3]=o3;
        }
    }

    float bias[3][2];
    #pragma unroll
    for (int nt = 0; nt < 2; ++nt) {
        int ch = nh*32 + nt*16 + l15;
        bias[0][nt] = b1[ch];
        bias[1][nt] = b2[ch];
        bias[2][nt] = b3[ch];
    }

    floatx4 acc[3][2][2];
    #pragma unroll
    for (int g = 0; g < 3; ++g)
        #pragma unroll
        for (int mt = 0; mt < 2; ++mt)
            #pragma unroll
            for (int nt = 0; nt < 2; ++nt)
                acc[g][mt][nt] = (floatx4){0.f,0.f,0.f,0.f};

    __syncthreads();                        // A ready; only barrier before epilogue

    #pragma unroll 1
    for (int ks = 0; ks < 10; ++ks) {
        short8 af[2][3];                    // tap-shifted A rows shared by grams
        #pragma unroll
        for (int mt = 0; mt < 2; ++mt)
            #pragma unroll
            for (int j = 0; j < 3; ++j)
                af[mt][j] = *(const short8*)(As + (mh*32 + mt*16 + l15 + j)*656 + ks*64 + qd4*16);
        const u16* Wks = Wt3 + ks*24576;    // 48 KB K-slice, L2-hot
        #pragma unroll
        for (int g = 0; g < 3; ++g) {
            const int cbW = (g == 0) ? 0 : (g == 1) ? 4096 : 12288;  // u16 units
            #pragma unroll
            for (int j = 0; j <= g; ++j) {
                const u16* bb = Wks + cbW + (j*8 + nh*2)*512 + lane*8;
                short8 w0  = *(const short8*)(bb);
                short8 w1v = *(const short8*)(bb + 512);
                #pragma unroll
                for (int mt = 0; mt < 2; ++mt) {
                    acc[g][mt][0] = __builtin_amdgcn_mfma_f32_16x16x32_bf16(
                        af[mt][j], w0,  acc[g][mt][0], 0, 0, 0);
                    acc[g][mt][1] = __builtin_amdgcn_mfma_f32_16x16x32_bf16(
                        af[mt][j], w1v, acc[g][mt][1], 0, 0, 0);
                }
            }
        }
    }

    // epilogue: per-gram Gs overlay on As (dead after K loop).
    // FULLY UNROLLED over g -> acc/bias stay compile-time indexed (no scratch).
    u16* Gs = (u16*)smem;                   // [64][136]
    #pragma unroll
    for (int g = 0; g < 3; ++g) {
        __syncthreads();                    // Gs region free (A reads / prev g done)
        #pragma unroll
        for (int mt = 0; mt < 2; ++mt)
            #pragma unroll
            for (int nt = 0; nt < 2; ++nt) {
                int ch = nh*32 + nt*16 + l15;
                #pragma unroll
                for (int i = 0; i < 4; ++i) {
                    int row = mh*32 + mt*16 + qd4*4 + i;
                    Gs[row*136 + ch] = f2b(fmaxf(acc[g][mt][nt][i] + bias[g][nt], 0.f));
                }
            }
        __syncthreads();

        if (tid < 64) {
            const char* rp = (const char*)Gs + tid*272;
            float ssum = 0.f;
            #pragma unroll
            for (int t16 = 0; t16 < 16; ++t16) {
                uint4 u = *(const uint4*)(rp + t16*16);
                float x;
                x = bits2f(u.x << 16); ssum += x*x;  x = bits2f(u.x & 0xffff0000u); ssum += x*x;
                x = bits2f(u.y << 16); ssum += x*x;  x = bits2f(u.y & 0xffff0000u); ssum += x*x;
                x = bits2f(u.z << 16); ssum += x*x;  x = bits2f(u.z & 0xffff0000u); ssum += x*x;
                x = bits2f(u.w << 16); ssum += x*x;  x = bits2f(u.w & 0xffff0000u); ssum += x*x;
            }
            float inv = 1.f / (sqrtf(ssum) + 1e-13f);
            int gr = gR0 + tid;
            int b = gr >> 8, pos = gr & 255;
            if (pos < 208)      invnd[(g*B_ + b)*208 + pos] = inv;
            else if (pos < 238) invnq[(g*B_ + b)*32 + (pos - 208)] = inv;
        }
        #pragma unroll
        for (int i = 0; i < 2; ++i) {
            int idx = tid + i*512;          // 64 rows x 16 uint4
            int r = idx >> 4, c16 = idx & 15;
            uint4 v = *(const uint4*)((const char*)Gs + r*272 + c16*16);
            int gr = gR0 + r;
            int b = gr >> 8, pos = gr & 255;
            if (pos < 208)      *(uint4*)(dg + ((g*B_ + b)*208 + pos)*128 + c16*8) = v;
            else if (pos < 238) *(uint4*)(qg + ((g*B_ + b)*32 + (pos - 208))*128 + c16*8) = v;
        }
    }
}

// ---------------------------------------------------------------------------
// Pool: block per (dj, b); grid (3, 128) -> 384 blocks.  (unchanged)
// ---------------------------------------------------------------------------
__global__ __launch_bounds__(256, 2) void pool_kernel(
    const u16* __restrict__ qg, const u16* __restrict__ dg,
    const float* __restrict__ invnq, const float* __restrict__ invnd,
    const int* __restrict__ qtok, const int* __restrict__ dtok,
    float* __restrict__ feats)
{
    __shared__ __align__(16) u16 dsb[208*136];     // 56576 B
    __shared__ float pk[96*12];                    // 4608 B
    __shared__ float invqA[96];
    __shared__ float qmA[96];
    __shared__ __align__(16) float invd[208];

    const int tid = threadIdx.x;
    const int b = blockIdx.y, dj = blockIdx.x;
    const int wv = tid >> 6, lane = tid & 63;
    const int l15 = lane & 15, qd4 = lane >> 4;

    for (int idx = tid; idx < 208*16; idx += 256) {
        int r = idx >> 4, ch = idx & 15;
        uint4 v = make_uint4(0u,0u,0u,0u);
        if (r < Dn) v = *(const uint4*)(dg + ((dj*B_ + b)*208 + r)*128 + ch*8);
        *(uint4*)((char*)dsb + r*272 + ch*16) = v;
    }
    if (tid < 208) {
        float v = invnd[(dj*B_ + b)*208 + tid];
        bool ok = (tid < Dn) && (dtok[b*Dn + tid] > 0);
        invd[tid] = ok ? v : (-fabsf(v) - 1.0f);   // strictly negative if masked
    }
    if (tid < 96) {
        int qi = tid >> 5, qr = tid & 31;
        float v = invnq[(qi*B_ + b)*32 + qr];
        bool ok = (qr < Qn) && (qtok[b*Qn + qr] > 0);
        invqA[tid] = ok ? v : 0.f;
        qmA[tid] = ok ? 1.f : 0.f;
    }
    for (int i = tid; i < 96*12; i += 256) pk[i] = 0.f;
    __syncthreads();

    // chain constants C_k = exp(10*(mu_k + mu_{k+1})), mu: 0.9,0.7,...,-0.9
    const float CkR[9] = {8886110.5f, 162754.79f, 2980.958f, 54.598150f, 1.0f,
                          0.018315639f, 3.3546263e-4f, 6.1442124e-6f, 1.1253517e-7f};

    for (int qi = 0; qi < 3; ++qi) {
        short8 qf[2][4];
        float vq[2];
        #pragma unroll
        for (int qt = 0; qt < 2; ++qt) {
            vq[qt] = invqA[qi*32 + qt*16 + l15];
            #pragma unroll
            for (int ks = 0; ks < 4; ++ks)
                qf[qt][ks] = *(const short8*)(qg + ((qi*B_ + b)*32 + qt*16 + l15)*128 + ks*32 + qd4*8);
        }
        float pkl[2][11];
        #pragma unroll
        for (int qt = 0; qt < 2; ++qt)
            #pragma unroll
            for (int k = 0; k < 11; ++k) pkl[qt][k] = 0.f;

        for (int t = wv; t < 13; t += 4) {
            short8 af[4];
            #pragma unroll
            for (int ks = 0; ks < 4; ++ks)
                af[ks] = *(const short8*)((const char*)dsb + (t*16 + l15)*272 + ks*64 + qd4*16);
            floatx4 acc[2];
            acc[0] = (floatx4){0.f,0.f,0.f,0.f};
            acc[1] = (floatx4){0.f,0.f,0.f,0.f};
            #pragma unroll
            for (int ks = 0; ks < 4; ++ks)
                #pragma unroll
                for (int qt = 0; qt < 2; ++qt)
                    acc[qt] = __builtin_amdgcn_mfma_f32_16x16x32_bf16(af[ks], qf[qt][ks], acc[qt], 0, 0, 0);
            floatx4 iv4 = *(const floatx4*)(invd + t*16 + qd4*4);
            #pragma unroll
            for (int qt = 0; qt < 2; ++qt)
                #pragma unroll
                for (int i = 0; i < 4; ++i) {
                    float cs = acc[qt][i] * vq[qt] * iv4[i];
                    cs = (cs > 0.f) ? cs : 2.0f;   // masked/zero -> all kernels ~0
                    float t0 = cs - 1.0f;
                    float u  = cs - 0.9f;
                    float s0 = __expf(-500000.f * t0 * t0);
                    float e  = __expf(-50.f * u * u);
                    float rr = __expf(-20.f * cs);
                    pkl[qt][0] += s0;
                    pkl[qt][1] += e;
                    #pragma unroll
                    for (int kk = 0; kk < 9; ++kk) {
                        e = e * rr * CkR[kk];
                        pkl[qt][2 + kk] += e;
                    }
                }
        }
        #pragma unroll
        for (int qt = 0; qt < 2; ++qt)
            #pragma unroll
            for (int k = 0; k < 11; ++k) {
                float v = pkl[qt][k];
                v += __shfl_xor(v, 16);
                v += __shfl_xor(v, 32);
                if (qd4 == 0) atomicAdd(&pk[(qi*32 + qt*16 + l15)*12 + k], v);
            }
    }
    __syncthreads();

    if (tid < 33) {
        int qi = tid / 11, k = tid - qi*11;
        float s = 0.f;
        for (int q = 0; q < Qn; ++q)
            s += qmA[qi*32 + q] * 0.01f * __logf(fmaxf(pk[(qi*32 + q)*12 + k], 1e-10f));
        feats[(b*9 + qi*3 + dj)*11 + k] = s;
    }
}

// ---------------------------------------------------------------------------
__global__ void final_kernel(const float* __restrict__ feats,
                             const float* __restrict__ dw,
                             float* __restrict__ out) {
    int b = threadIdx.x;
    if (b < B_) {
        float s = 0.f;
        for (int f = 0; f < 99; ++f) s += feats[b*99 + f] * dw[f];
        out[b] = s;
    }
}

extern "C" void kernel_launch(void* const* d_in, const int* in_sizes, int n_in,
                              void* d_out, int out_size, void* d_ws, size_t ws_size,
                              hipStream_t stream) {
    const int*   qtok = (const int*)d_in[0];
    const int*   dtok = (const int*)d_in[1];
    const float* emb  = (const float*)d_in[2];
    const float* w1   = (const float*)d_in[3];
    const float* w2   = (const float*)d_in[4];
    const float* w3   = (const float*)d_in[5];
    const float* b1   = (const float*)d_in[6];
    const float* b2   = (const float*)d_in[7];
    const float* b3   = (const float*)d_in[8];
    const float* dw   = (const float*)d_in[9];
    float* out = (float*)d_out;

    char* w = (char*)d_ws;
    u16*   Wt3   = (u16*)w;                      // 491,520 B
    u16*   qg    = (u16*)(w + 491520);           // 3*128*32*128*2  = 3,145,728
    u16*   dgm   = (u16*)(w + 3637248);          // 3*128*208*128*2 = 20,447,232
    float* invq_ = (float*)(w + 24084480);       // 49,152
    float* invd_ = (float*)(w + 24133632);       // 319,488
    float* feats = (float*)(w + 24453120);       // 50,688 -> total 24,503,808

    prep_kernel<<<dim3(8, B_), 256, 0, stream>>>(w1, w2, w3, Wt3);

    conv_kernel<<<dim3(512), 512, 0, stream>>>(
        qtok, dtok, emb, Wt3, b1, b2, b3, qg, dgm, invq_, invd_);

    pool_kernel<<<dim3(3, B_), 256, 0, stream>>>(qg, dgm, invq_, invd_, qtok, dtok, feats);

    final_kernel<<<1, 128, 0, stream>>>(feats, dw, out);
}